// Round 1
// 549.176 us; speedup vs baseline: 1.1114x; 1.1114x over previous
//
#include <hip/hip_runtime.h>
#include <hip/hip_bf16.h>
#include <math.h>

#define TOK 4096
#define HD 1024
#define FD 4096
#define NE 8

typedef __attribute__((ext_vector_type(4))) float f32x4;
typedef __attribute__((ext_vector_type(8))) short s16x8;
typedef __attribute__((ext_vector_type(4))) unsigned int u32x4;

typedef const __attribute__((address_space(1))) void g_void;
typedef __attribute__((address_space(3))) void lds_void;

__device__ __forceinline__ unsigned short f2bf(float f) {
    union { float f; unsigned u; } v; v.f = f;
    unsigned r = v.u + 0x7FFFu + ((v.u >> 16) & 1u);   // RNE
    return (unsigned short)(r >> 16);
}

// v_cvt_pk_bf16_f32: lo16 = bf16(a), hi16 = bf16(b), RNE (exists on gfx950, T12)
__device__ __forceinline__ unsigned cvt2(float a, float b) {
    unsigned r;
    asm("v_cvt_pk_bf16_f32 %0, %1, %2" : "=v"(r) : "v"(a), "v"(b));
    return r;
}

// ---------------- router: sigmoid(x@Wr+br), top-1, compact lists, cast x->bf16
__global__ void router_kernel(const float* __restrict__ x, const float* __restrict__ Wr,
                              const float* __restrict__ br, int* __restrict__ counts,
                              int* __restrict__ tlist, float* __restrict__ mprob,
                              unsigned short* __restrict__ xb) {
    const int lane = threadIdx.x & 63;
    const int t = blockIdx.x * 4 + (threadIdx.x >> 6);
    const float* xr = x + (size_t)t * HD;
    unsigned short* xbr = xb + (size_t)t * HD;
    float acc[NE];
#pragma unroll
    for (int e = 0; e < NE; ++e) acc[e] = 0.f;
    for (int h = lane; h < HD; h += 64) {
        float xv = xr[h];
        xbr[h] = f2bf(xv);                          // coalesced bf16 cast-out
        f32x4 w0 = *(const f32x4*)(Wr + h * NE);
        f32x4 w1 = *(const f32x4*)(Wr + h * NE + 4);
        acc[0] += xv * w0.x; acc[1] += xv * w0.y; acc[2] += xv * w0.z; acc[3] += xv * w0.w;
        acc[4] += xv * w1.x; acc[5] += xv * w1.y; acc[6] += xv * w1.z; acc[7] += xv * w1.w;
    }
#pragma unroll
    for (int off = 32; off >= 1; off >>= 1)
#pragma unroll
        for (int e = 0; e < NE; ++e) acc[e] += __shfl_down(acc[e], off, 64);
    if (lane == 0) {
        float best = -1.f; int bi = 0;
#pragma unroll
        for (int e = 0; e < NE; ++e) {
            float r = 1.f / (1.f + expf(-(acc[e] + br[e])));
            if (r > best) { best = r; bi = e; }   // strict > keeps first index on tie
        }
        mprob[t] = best;
        int pos = atomicAdd(&counts[bi], 1);
        tlist[bi * TOK + pos] = t;
    }
}

// ---------------- gathered expert GEMM, fp32 weights consumed in-place ---------
// B (weights) stay in NATIVE [E][K][N] fp32 layout: per 64-K step we DMA the
// [64k][128n] fp32 tile lane-linear into Braw (coalesced), then an LDS->LDS
// convert phase transposes+casts into the XOR-swizzled bf16 [n][k] layout Bl
// (all b128 accesses land at the wave64 8-phase minimum -> conflict-free).
// K-loop is the T3 minimum 2-phase pipeline: raw barriers (no vmcnt drain in
// barrier), DMA(t+1) issued between barriers so HBM latency hides under
// compute(t). A is double-buffered; Braw/Bl single (convert->compute same iter).
// LDS = 32K(A dbuf) + 32K(Braw) + 16K(Bl) = 80 KB -> 2 blocks/CU.
template<int K, bool FC1, int KSPLIT>
__global__ __launch_bounds__(256, 2)
void expert_gemm(const unsigned short* __restrict__ Asrc, const float* __restrict__ Wsrc,
                 const int* __restrict__ counts, const int* __restrict__ tlist,
                 const float* __restrict__ mprob,
                 unsigned short* __restrict__ inter, float* __restrict__ out) {
    constexpr int NDIM = FC1 ? FD : HD;
    constexpr int KC = K / KSPLIT;
    constexpr int NT = KC / 64;
    const int e  = (KSPLIT == 1) ? blockIdx.z : ((int)blockIdx.z & (NE - 1));
    const int ks = (KSPLIT == 1) ? 0 : ((int)blockIdx.z >> 3);
    const int kbase = ks * KC;
    const int cnt = counts[e];
    const int m0 = blockIdx.y * 128;
    if (m0 >= cnt) return;
    const int n0 = blockIdx.x * 128;

    __shared__ unsigned short Al[2][128 * 64];
    __shared__ float Braw[64 * 128];
    __shared__ unsigned short Bl[128 * 64];

    const int tid = threadIdx.x;
    const int lane = tid & 63;
    const int wave = tid >> 6;

    // A staging: swizzled-global so lane-linear LDS slot (r,g) holds k-group (g-r)&7
    const unsigned short* aptr[4];
    {
        int lr = lane >> 3, g = lane & 7;
#pragma unroll
        for (int it = 0; it < 4; ++it) {
            int r = wave * 32 + it * 8 + lr;
            int kg = (g - r) & 7;
            int m = m0 + r;
            int tk = (m < cnt) ? tlist[e * TOK + m] : 0;  // clamp: row discarded in epilogue
            aptr[it] = Asrc + (size_t)tk * K + kbase + kg * 8;
        }
    }
    // B staging: fp32, 2 k-rows per gload_lds (lane>>5 = sub-row, (lane&31)*4 = col)
    const float* bptr = Wsrc + ((size_t)e * K + kbase + wave * 16 + (lane >> 5)) * NDIM
                        + n0 + ((lane & 31) << 2);

    const int wrow = (wave >> 1) << 6;
    const int wcol = (wave & 1) << 6;
    const int lm = lane & 15, quad = lane >> 4;
    const int cg = tid >> 3;      // convert: n-group 0..31 (4 cols each)
    const int gg = tid & 7;       // convert: k-group 0..7 (8 rows each)

    f32x4 acc[4][4] = {};

    // ---- DMA(0)
#pragma unroll
    for (int it = 0; it < 4; ++it)
        __builtin_amdgcn_global_load_lds((g_void*)aptr[it],
            (lds_void*)&Al[0][wave * 2048 + it * 512], 16, 0, 0);
#pragma unroll
    for (int L = 0; L < 8; ++L)
        __builtin_amdgcn_global_load_lds((g_void*)(bptr + (size_t)(L * 2) * NDIM),
            (lds_void*)&Braw[(wave * 16 + L * 2) * 128], 16, 0, 0);

    for (int t = 0; t < NT; ++t) {
        const int buf = t & 1;
        // barrier A: own DMA(t) landed + everyone's; no reader of Bl/Al[buf] remains
        asm volatile("s_waitcnt vmcnt(0) lgkmcnt(0)\n\ts_barrier" ::: "memory");

        // ---- convert Braw[64k][128n] f32 -> Bl[n][k] bf16 (swizzled slots)
        {
            f32x4 v[8];
#pragma unroll
            for (int j = 0; j < 8; ++j)
                v[j] = *(const f32x4*)&Braw[(gg * 8 + j) * 128 + (cg << 2)];
#pragma unroll
            for (int i = 0; i < 4; ++i) {
                int n = (cg << 2) + i;
                u32x4 q;
                q.x = cvt2(v[0][i], v[1][i]);
                q.y = cvt2(v[2][i], v[3][i]);
                q.z = cvt2(v[4][i], v[5][i]);
                q.w = cvt2(v[6][i], v[7][i]);
                *(u32x4*)&Bl[(n << 6) + (((gg + n) & 7) << 3)] = q;
            }
        }
        // barrier B: Bl visible to all; Braw free for next DMA
        asm volatile("s_waitcnt lgkmcnt(0)\n\ts_barrier" ::: "memory");

        // ---- prefetch DMA(t+1) — flies under compute(t)
        if (t + 1 < NT) {
#pragma unroll
            for (int it = 0; it < 4; ++it) {
                aptr[it] += 64;
                __builtin_amdgcn_global_load_lds((g_void*)aptr[it],
                    (lds_void*)&Al[buf ^ 1][wave * 2048 + it * 512], 16, 0, 0);
            }
            bptr += (size_t)64 * NDIM;
#pragma unroll
            for (int L = 0; L < 8; ++L)
                __builtin_amdgcn_global_load_lds((g_void*)(bptr + (size_t)(L * 2) * NDIM),
                    (lds_void*)&Braw[(wave * 16 + L * 2) * 128], 16, 0, 0);
            __builtin_amdgcn_sched_barrier(0);   // keep DMA issue ahead of frag reads
        }

        // ---- compute(t)
#pragma unroll
        for (int kt = 0; kt < 2; ++kt) {
            s16x8 af[4], bf[4];
            int gk = (kt << 2) + quad;
#pragma unroll
            for (int mt = 0; mt < 4; ++mt) {
                int m = wrow + (mt << 4) + lm;
                af[mt] = *(const s16x8*)&Al[buf][(m << 6) + (((gk + m) & 7) << 3)];
            }
#pragma unroll
            for (int nt = 0; nt < 4; ++nt) {
                int n = wcol + (nt << 4) + lm;
                bf[nt] = *(const s16x8*)&Bl[(n << 6) + (((gk + n) & 7) << 3)];
            }
#pragma unroll
            for (int mt = 0; mt < 4; ++mt)
#pragma unroll
                for (int nt = 0; nt < 4; ++nt)
                    acc[mt][nt] = __builtin_amdgcn_mfma_f32_16x16x32_bf16(
                        af[mt], bf[nt], acc[mt][nt], 0, 0, 0);
        }
    }

    // ---- epilogue: C/D layout col=lane&15, row=quad*4+reg. tlist/mprob reloads
    // are 16 broadcast dword loads/thread (L1-hot) — cheaper than LDS + prologue barrier.
#pragma unroll
    for (int mt = 0; mt < 4; ++mt) {
#pragma unroll
        for (int r = 0; r < 4; ++r) {
            int row = wrow + (mt << 4) + (quad << 2) + r;
            if (m0 + row >= cnt) continue;
            int tk = tlist[e * TOK + m0 + row];
            int colb = n0 + wcol + lm;
            if constexpr (FC1) {
#pragma unroll
                for (int nt = 0; nt < 4; ++nt) {
                    float v = acc[mt][nt][r];
                    float g = 0.5f * v * (1.f + erff(v * 0.70710678f));  // exact gelu
                    inter[(size_t)tk * FD + colb + (nt << 4)] = f2bf(g);
                }
            } else {
                float p = mprob[tk];
#pragma unroll
                for (int nt = 0; nt < 4; ++nt)
                    atomicAdd(&out[(size_t)tk * HD + colb + (nt << 4)], acc[mt][nt][r] * p);
            }
        }
    }
}

extern "C" void kernel_launch(void* const* d_in, const int* in_sizes, int n_in,
                              void* d_out, int out_size, void* d_ws, size_t ws_size,
                              hipStream_t stream) {
    const float* x  = (const float*)d_in[0];
    const float* Wr = (const float*)d_in[1];
    const float* br = (const float*)d_in[2];
    const float* W1 = (const float*)d_in[3];
    const float* W2 = (const float*)d_in[4];
    float* out = (float*)d_out;

    char* ws = (char*)d_ws;
    int* counts           = (int*)ws;                           // 32 B (pad 256)
    float* mprob          = (float*)(ws + 256);                 // 16 KB
    int* tlist            = (int*)(ws + 16640);                 // 128 KB
    unsigned short* xb    = (unsigned short*)(ws + 147712);     // TOK*HD bf16, 8 MB
    unsigned short* inter = (unsigned short*)(ws + 8536320);    // TOK*FD bf16, 32 MB
    // no Wt buffer anymore: fp32 weights consumed directly by the GEMMs

    hipMemsetAsync(counts, 0, NE * sizeof(int), stream);
    hipMemsetAsync(out, 0, (size_t)out_size * sizeof(float), stream);  // split-K accumulates
    router_kernel<<<TOK / 4, 256, 0, stream>>>(x, Wr, br, counts, tlist, mprob, xb);

    // fc1: gelu(x @ W1) -> inter (bf16).  x = N-blocks (all live -> XCD spread)
    expert_gemm<HD, true, 1><<<dim3(FD / 128, TOK / 128, NE), 256, 0, stream>>>(
        xb, W1, counts, tlist, mprob, inter, nullptr);

    // fc2: (inter @ W2) * max_prob -> out (fp32), split-K=2, atomic accumulate
    expert_gemm<FD, false, 2><<<dim3(HD / 128, TOK / 128, NE * 2), 256, 0, stream>>>(
        inter, W2, counts, tlist, mprob, nullptr, out);
}